// Round 6
// baseline (502.931 us; speedup 1.0000x reference)
//
#include <hip/hip_runtime.h>

// Social-STGCN forward: 2x GCN(improved) + 3x GCLSTM(K=3 Cheb, H=C=0) + linear.
// N=50000 nodes, E=800000 edges, D=64.
//
// Exact simplifications (H=C=0 per cell): gh(g)=bh[g]; f gate dead; Cn=i*t.
// Cheb terms z1=lhat(x), z2=2*lhat(z1)-x shared across gates.
// Aggregation commutes with feature matmul -> GCNs gather raw features first.
// 64-dim gathers are FEATURE-SPLIT (gridDim.y=2, 32 feats each): per-pass src
// slab = 3.2MB -> per-XCD L2-resident (full 6.4MB table exceeds 4MiB L2/XCD).
// Gate matmul + GCN2 matmul on MFMA fp16; layer-3 gate fuses relu+linear.
// csr_src stored as ushort (N<65536).

typedef _Float16 half8 __attribute__((ext_vector_type(8)));
typedef float f32x4 __attribute__((ext_vector_type(4)));

// ---------- CSR build ----------
__global__ void count_deg_kernel(const int* __restrict__ ei, int* __restrict__ deg, int E) {
  int e = blockIdx.x * blockDim.x + threadIdx.x;
  if (e < E) atomicAdd(&deg[ei[E + e]], 1);
}

__global__ void scan_block_sums(const int* __restrict__ deg, int* __restrict__ bsum, int n) {
  int tid = threadIdx.x;
  int i = blockIdx.x * 256 + tid;
  int v = (i < n) ? deg[i] : 0;
  for (int off = 32; off; off >>= 1) v += __shfl_down(v, off);
  __shared__ int ws[4];
  int lane = tid & 63, wid = tid >> 6;
  if (lane == 0) ws[wid] = v;
  __syncthreads();
  if (tid == 0) bsum[blockIdx.x] = ws[0] + ws[1] + ws[2] + ws[3];
}

// per-block exclusive scan of deg + block offset computed in-block from raw bsum;
// also fills cursor and both dinv arrays.
__global__ void scan_final(const int* __restrict__ deg, const int* __restrict__ bsum, int nb,
                           int* __restrict__ rowptr, int* __restrict__ cursor,
                           float* __restrict__ dg, float* __restrict__ dc, int n) {
  __shared__ int tmp[256];
  __shared__ int ws[4];
  __shared__ int base_sh;
  int tid = threadIdx.x;
  int v0 = (tid < nb && tid < (int)blockIdx.x) ? bsum[tid] : 0;
  for (int off = 32; off; off >>= 1) v0 += __shfl_down(v0, off);
  if ((tid & 63) == 0) ws[tid >> 6] = v0;
  __syncthreads();
  if (tid == 0) base_sh = ws[0] + ws[1] + ws[2] + ws[3];
  int i = blockIdx.x * 256 + tid;
  int v = (i < n) ? deg[i] : 0;
  tmp[tid] = v;
  __syncthreads();
  for (int off = 1; off < 256; off <<= 1) {
    int t = (tid >= off) ? tmp[tid - off] : 0;
    __syncthreads();
    tmp[tid] += t;
    __syncthreads();
  }
  if (i < n) {
    int excl = tmp[tid] - v + base_sh;
    rowptr[i] = excl;
    cursor[i] = excl;
    dg[i] = rsqrtf((float)v + 2.f);
    dc[i] = (v > 0) ? rsqrtf((float)v) : 0.f;
  }
}

__global__ void fill_kernel(const int* __restrict__ ei, int* __restrict__ cursor,
                            unsigned short* __restrict__ csr, int E) {
  int e = blockIdx.x * blockDim.x + threadIdx.x;
  if (e < E) {
    int d = ei[E + e];
    int pos = atomicAdd(&cursor[d], 1);
    csr[pos] = (unsigned short)ei[e];
  }
}

// ---------- cast x (N x 16 fp32) -> fp16 ----------
__global__ void cast_x16_kernel(const float* __restrict__ x, _Float16* __restrict__ x16, int total) {
  int i = blockIdx.x * blockDim.x + threadIdx.x;
  if (i < total) x16[i] = (_Float16)x[i];
}

// ---------- pack gate weights -> fp16 MFMA B-fragment layout ----------
// Wpk[l][g][kc][nt][lane][j]; g in {i,c,o} = src gates {0,2,3}; k = kc*32 + klo,
// klo = (lane>>4)*8 + j; n = nt*16 + (lane&15). Source wx: [4][3][64][64].
__global__ void pack_w_kernel(const float* __restrict__ wx0, const float* __restrict__ wx1,
                              const float* __restrict__ wx2, _Float16* __restrict__ Wpk) {
  int idx = blockIdx.x * 256 + threadIdx.x;
  if (idx >= 3 * 3 * 192 * 64) return;
  int l = idx / 36864;
  int r = idx % 36864;
  int g = r / 12288;
  int r2 = r % 12288;
  int k = r2 / 64;   // 0..191
  int n = r2 % 64;
  const float* wx = (l == 0) ? wx0 : (l == 1 ? wx1 : wx2);
  int gs = (g == 0) ? 0 : (g == 1 ? 2 : 3);
  int tau = k >> 6, kd = k & 63;
  float v = wx[(((size_t)gs * 3 + tau) * 64 + kd) * 64 + n];
  int kc = k >> 5, klo = k & 31;
  int lane = ((klo >> 3) << 4) | (n & 15);
  int j = klo & 7;
  int nt = n >> 4;
  size_t dst = ((((size_t)l * 3 + g) * 6 + kc) * 4 + nt) * 512 + (size_t)lane * 8 + j;
  Wpk[dst] = (_Float16)v;
}

// ---------- pack w_gcn2 [64][64] -> B-frag layout [kc2][nt4][lane][8] ----------
__global__ void pack_w2_kernel(const float* __restrict__ W, _Float16* __restrict__ Wpk2) {
  int idx = blockIdx.x * 256 + threadIdx.x;
  if (idx >= 4096) return;
  int k = idx >> 6, n = idx & 63;
  float v = W[k * 64 + n];
  int kc = k >> 5, klo = k & 31;
  int lane = ((klo >> 3) << 4) | (n & 15);
  int j = klo & 7;
  int nt = n >> 4;
  Wpk2[(((size_t)kc * 4 + nt) * 64 + lane) * 8 + j] = (_Float16)v;
}

// ---------- gather16: GCN raw agg on 16-dim fp16 rows; 2 nodes/wave ----------
__global__ void gather16_kernel(const int* __restrict__ rowptr, const int* __restrict__ deg,
                                const unsigned short* __restrict__ csr,
                                const float* __restrict__ dinv,
                                const _Float16* __restrict__ X16,
                                _Float16* __restrict__ OUT, int n) {
  int tid = threadIdx.x;
  int node = blockIdx.x * (blockDim.x >> 5) + (tid >> 5);
  if (node >= n) return;
  int l32 = tid & 31;
  int eg = l32 >> 1;   // 16 edge slots
  int c8 = l32 & 1;    // half8 chunk (8 feats)
  int beg = rowptr[node], end = beg + deg[node];
  const half8* IN8 = (const half8*)X16;  // 2 per row
  float acc[8];
#pragma unroll
  for (int j = 0; j < 8; ++j) acc[j] = 0.f;
  for (int p = beg + eg; p < end; p += 16) {
    int s = csr[p];
    float dv = dinv[s];
    half8 v = IN8[(size_t)s * 2 + c8];
#pragma unroll
    for (int j = 0; j < 8; ++j) acc[j] += dv * (float)v[j];
  }
#pragma unroll
  for (int j = 0; j < 8; ++j) {
    acc[j] += __shfl_xor(acc[j], 2);
    acc[j] += __shfl_xor(acc[j], 4);
    acc[j] += __shfl_xor(acc[j], 8);
    acc[j] += __shfl_xor(acc[j], 16);
  }
  if (eg == 0) {
    float dt = dinv[node];
    float c2 = 2.f * dt * dt;
    half8 self = IN8[(size_t)node * 2 + c8];
    half8 r;
#pragma unroll
    for (int j = 0; j < 8; ++j) r[j] = (_Float16)(dt * acc[j] + c2 * (float)self[j]);
    ((half8*)OUT)[(size_t)node * 2 + c8] = r;
  }
}

// ---------- gather (64-dim, feature-split): gridDim.y=2 halves of 32 feats ----------
// Wave: 16 edge-slots x 4 lanes x half8. Per-pass src slab 3.2MB -> L2-resident.
// MODE 0: GCN raw -> OUT = dt*acc + 2*dt^2*IN[node]
// MODE 1: z1      -> OUT = -dt*acc
// MODE 2: z2      -> OUT = -2*dt*acc - AUX[node]
template <int MODE>
__global__ void gather_kernel(const int* __restrict__ rowptr, const int* __restrict__ deg,
                              const unsigned short* __restrict__ csr,
                              const float* __restrict__ dinv,
                              const _Float16* __restrict__ IN, const _Float16* __restrict__ AUX,
                              _Float16* __restrict__ OUT, int n) {
  int node = blockIdx.x * (blockDim.x >> 6) + (threadIdx.x >> 6);
  if (node >= n) return;
  int lane = threadIdx.x & 63;
  int eg = lane >> 2;                          // 16 edge slots
  int ch = (blockIdx.y << 2) | (lane & 3);     // half8 chunk 0..7 of the row
  int beg = rowptr[node], end = beg + deg[node];
  const half8* IN8 = (const half8*)IN;
  float acc[8];
#pragma unroll
  for (int j = 0; j < 8; ++j) acc[j] = 0.f;
  for (int p = beg + eg; p < end; p += 16) {
    int s = csr[p];
    float dv = dinv[s];
    half8 v = IN8[(size_t)s * 8 + ch];
#pragma unroll
    for (int j = 0; j < 8; ++j) acc[j] += dv * (float)v[j];
  }
  // reduce across the 16 edge slots (lane bits 2..5)
#pragma unroll
  for (int j = 0; j < 8; ++j) {
    acc[j] += __shfl_xor(acc[j], 4);
    acc[j] += __shfl_xor(acc[j], 8);
    acc[j] += __shfl_xor(acc[j], 16);
    acc[j] += __shfl_xor(acc[j], 32);
  }
  if (eg == 0) {
    float dt = dinv[node];
    size_t o8 = (size_t)node * 8 + ch;
    half8 r;
    if (MODE == 0) {
      half8 self = IN8[o8];
      float c2 = 2.f * dt * dt;
#pragma unroll
      for (int j = 0; j < 8; ++j) r[j] = (_Float16)(dt * acc[j] + c2 * (float)self[j]);
    } else if (MODE == 1) {
#pragma unroll
      for (int j = 0; j < 8; ++j) r[j] = (_Float16)(-dt * acc[j]);
    } else {
      half8 xx = ((const half8*)AUX)[o8];
#pragma unroll
      for (int j = 0; j < 8; ++j) r[j] = (_Float16)(-2.f * dt * acc[j] - (float)xx[j]);
    }
    ((half8*)OUT)[o8] = r;
  }
}

// ---------- GCN1: h1 = relu(A16[n][16] @ W[16][64] + b)  (fp16 in/out) ----------
__global__ __launch_bounds__(64) void rowmm16f_kernel(const _Float16* __restrict__ A,
                                                      const float* __restrict__ W,
                                                      const float* __restrict__ bias,
                                                      _Float16* __restrict__ OUT, int n) {
  __shared__ float xt[256];
  int tid = threadIdx.x;
  int n0 = blockIdx.x * 16;
  for (int idx = tid; idx < 256; idx += 64) {
    int row = idx >> 4, col = idx & 15;
    int gr = min(n0 + row, n - 1);
    xt[idx] = (float)A[(size_t)gr * 16 + col];
  }
  __syncthreads();
  float acc[16];
  float b = bias[tid];
#pragma unroll
  for (int t = 0; t < 16; ++t) acc[t] = b;
  for (int k = 0; k < 16; ++k) {
    float w = W[k * 64 + tid];
#pragma unroll
    for (int t = 0; t < 16; ++t) acc[t] += xt[t * 16 + k] * w;
  }
#pragma unroll
  for (int t = 0; t < 16; ++t) {
    int node = n0 + t;
    if (node < n) OUT[(size_t)node * 64 + tid] = (_Float16)fmaxf(acc[t], 0.f);
  }
}

// ---------- GCN2 on MFMA: h2 = relu(A[n][64] @ W2 + b) ----------
__global__ __launch_bounds__(256) void gcn2_mfma_kernel(
    const _Float16* __restrict__ A, const _Float16* __restrict__ W2,
    const float* __restrict__ bias, _Float16* __restrict__ OUT, int n) {
  int tid = threadIdx.x;
  int wid = tid >> 6, lane = tid & 63;
  int n0 = blockIdx.x * 64;
  int row = n0 + wid * 16 + (lane & 15);
  int rowc = min(row, n - 1);
  int ksub = (lane >> 4) << 3;
  int dbase = lane & 15;
  const _Float16* Wlane = W2 + (size_t)lane * 8;
  f32x4 acc[4];
#pragma unroll
  for (int nt = 0; nt < 4; ++nt) {
    float b = bias[nt * 16 + dbase];
    acc[nt] = (f32x4){b, b, b, b};
  }
#pragma unroll
  for (int kc = 0; kc < 2; ++kc) {
    half8 a = *(const half8*)&A[(size_t)rowc * 64 + (kc << 5) + ksub];
#pragma unroll
    for (int nt = 0; nt < 4; ++nt) {
      half8 b = *(const half8*)(Wlane + (size_t)(kc * 4 + nt) * 512);
      acc[nt] = __builtin_amdgcn_mfma_f32_16x16x32_f16(a, b, acc[nt], 0, 0, 0);
    }
  }
  int mrow = n0 + wid * 16 + ((lane >> 4) << 2);
#pragma unroll
  for (int nt = 0; nt < 4; ++nt) {
    int d = nt * 16 + dbase;
#pragma unroll
    for (int r = 0; r < 4; ++r) {
      int node = mrow + r;
      if (node < n) OUT[(size_t)node * 64 + d] = (_Float16)fmaxf(acc[nt][r], 0.f);
    }
  }
}

// ---------- MFMA gate kernel: 64 nodes/block, 16 nodes/wave, no LDS ----------
// FINAL=1: fuse out = relu(H) @ lin_w + lin_b (H never stored).
template <int FINAL>
__global__ __launch_bounds__(256) void gate_mfma_kernel(
    const _Float16* __restrict__ X, const _Float16* __restrict__ Z1,
    const _Float16* __restrict__ Z2,
    const _Float16* __restrict__ Wl,  // packed [3][6][4][64][8] for this layer
    const float* __restrict__ bx, const float* __restrict__ bh, const float* __restrict__ bg,
    const float* __restrict__ wc, _Float16* __restrict__ H,
    const float* __restrict__ lw, const float* __restrict__ lb,
    float* __restrict__ out, int n) {
  int tid = threadIdx.x;
  int wid = tid >> 6, lane = tid & 63;
  int n0 = blockIdx.x * 64;
  int row = n0 + wid * 16 + (lane & 15);
  int rowc = min(row, n - 1);               // clamped load row (stores guarded)
  int ksub = (lane >> 4) << 3;              // 0,8,16,24
  const _Float16* Wlane = Wl + (size_t)lane * 8;
  int dbase = lane & 15;

  f32x4 acc[3][4];
#pragma unroll
  for (int g = 0; g < 3; ++g) {
    int gs = (g == 0) ? 0 : (g == 1 ? 2 : 3);
#pragma unroll
    for (int nt = 0; nt < 4; ++nt) {
      int d = nt * 16 + dbase;
      float b = bx[gs * 64 + d] + bh[gs * 64 + d] + bg[gs * 64 + d];
      acc[g][nt] = (f32x4){b, b, b, b};
    }
  }
  const _Float16* T[3] = {X, Z1, Z2};
#pragma unroll
  for (int kc = 0; kc < 6; ++kc) {
    const _Float16* t = T[kc >> 1];
    half8 a = *(const half8*)&t[(size_t)rowc * 64 + ((kc & 1) << 5) + ksub];
#pragma unroll
    for (int g = 0; g < 3; ++g) {
#pragma unroll
      for (int nt = 0; nt < 4; ++nt) {
        half8 b = *(const half8*)(Wlane + (size_t)((g * 6 + kc) * 4 + nt) * 512);
        acc[g][nt] = __builtin_amdgcn_mfma_f32_16x16x32_f16(a, b, acc[g][nt], 0, 0, 0);
      }
    }
  }
  int mrow = n0 + wid * 16 + ((lane >> 4) << 2);
  float po[4][3];
  if (FINAL) {
#pragma unroll
    for (int r = 0; r < 4; ++r) { po[r][0] = 0.f; po[r][1] = 0.f; po[r][2] = 0.f; }
  }
#pragma unroll
  for (int nt = 0; nt < 4; ++nt) {
    int d = nt * 16 + dbase;
    float wcd = wc[128 + d];
#pragma unroll
    for (int r = 0; r < 4; ++r) {
      float ig = 1.f / (1.f + expf(-acc[0][nt][r]));
      float tt = tanhf(acc[1][nt][r]);
      float Cn = ig * tt;
      float og = 1.f / (1.f + expf(-(acc[2][nt][r] + wcd * Cn)));
      float h = og * tanhf(Cn);
      if (FINAL) {
        float rl = fmaxf(h, 0.f);
        po[r][0] += rl * lw[d * 3 + 0];
        po[r][1] += rl * lw[d * 3 + 1];
        po[r][2] += rl * lw[d * 3 + 2];
      } else {
        int node = mrow + r;
        if (node < n) H[(size_t)node * 64 + d] = (_Float16)h;
      }
    }
  }
  if (FINAL) {
#pragma unroll
    for (int m = 1; m < 16; m <<= 1) {
#pragma unroll
      for (int r = 0; r < 4; ++r) {
        po[r][0] += __shfl_xor(po[r][0], m);
        po[r][1] += __shfl_xor(po[r][1], m);
        po[r][2] += __shfl_xor(po[r][2], m);
      }
    }
    if (dbase == 0) {
#pragma unroll
      for (int r = 0; r < 4; ++r) {
        int node = mrow + r;
        if (node < n) {
          out[(size_t)node * 3 + 0] = po[r][0] + lb[0];
          out[(size_t)node * 3 + 1] = po[r][1] + lb[1];
          out[(size_t)node * 3 + 2] = po[r][2] + lb[2];
        }
      }
    }
  }
}

extern "C" void kernel_launch(void* const* d_in, const int* in_sizes, int n_in,
                              void* d_out, int out_size, void* d_ws, size_t ws_size,
                              hipStream_t stream) {
  const float* x      = (const float*)d_in[0];
  const int*   ei     = (const int*)d_in[1];
  const float* w_gcn1 = (const float*)d_in[2];
  const float* b_gcn1 = (const float*)d_in[3];
  const float* w_gcn2 = (const float*)d_in[4];
  const float* b_gcn2 = (const float*)d_in[5];
  const float* wx[3]  = {(const float*)d_in[6],  (const float*)d_in[12], (const float*)d_in[18]};
  const float* bx[3]  = {(const float*)d_in[7],  (const float*)d_in[13], (const float*)d_in[19]};
  const float* bh[3]  = {(const float*)d_in[9],  (const float*)d_in[15], (const float*)d_in[21]};
  const float* wc[3]  = {(const float*)d_in[10], (const float*)d_in[16], (const float*)d_in[22]};
  const float* bg[3]  = {(const float*)d_in[11], (const float*)d_in[17], (const float*)d_in[23]};
  const float* lin_w  = (const float*)d_in[24];
  const float* lin_b  = (const float*)d_in[25];
  float* out = (float*)d_out;

  int N = in_sizes[0] / 16;
  int E = in_sizes[1] / 2;
  int nsb = (N + 255) / 256;

  char* ws = (char*)d_ws;
  size_t off = 0;
  auto alloc = [&](size_t bytes) {
    void* p = ws + off;
    off = (off + bytes + 255) & ~(size_t)255;
    return p;
  };
  int* deg        = (int*)alloc((size_t)N * 4);
  int* rowptr     = (int*)alloc((size_t)N * 4);
  int* cursor     = (int*)alloc((size_t)N * 4);
  int* bsum       = (int*)alloc((size_t)nsb * 4);
  unsigned short* csr = (unsigned short*)alloc((size_t)E * 2);
  float* dinv_g   = (float*)alloc((size_t)N * 4);
  float* dinv_c   = (float*)alloc((size_t)N * 4);
  _Float16* Wpk   = (_Float16*)alloc((size_t)3 * 36864 * 2);
  _Float16* Wpk2  = (_Float16*)alloc((size_t)4096 * 2);
  _Float16* x16   = (_Float16*)alloc((size_t)N * 16 * 2);
  _Float16* a16   = (_Float16*)alloc((size_t)N * 16 * 2);
  _Float16* bufA  = (_Float16*)alloc((size_t)N * 64 * 2);
  _Float16* bufB  = (_Float16*)alloc((size_t)N * 64 * 2);
  _Float16* bufC  = (_Float16*)alloc((size_t)N * 64 * 2);
  (void)ws_size; (void)n_in; (void)out_size;

  const int tb = 256;
  hipMemsetAsync(deg, 0, (size_t)N * 4, stream);
  count_deg_kernel<<<(E + tb - 1) / tb, tb, 0, stream>>>(ei, deg, E);
  scan_block_sums<<<nsb, 256, 0, stream>>>(deg, bsum, N);
  scan_final<<<nsb, 256, 0, stream>>>(deg, bsum, nsb, rowptr, cursor, dinv_g, dinv_c, N);
  fill_kernel<<<(E + tb - 1) / tb, tb, 0, stream>>>(ei, cursor, csr, E);
  pack_w_kernel<<<(110592 + 255) / 256, 256, 0, stream>>>(wx[0], wx[1], wx[2], Wpk);
  pack_w2_kernel<<<16, 256, 0, stream>>>(w_gcn2, Wpk2);
  cast_x16_kernel<<<(N * 16 + 255) / 256, 256, 0, stream>>>(x, x16, N * 16);

  int nb16 = (N + 15) / 16;
  int nb64 = (N + 63) / 64;
  int nbw  = (N + 3) / 4;   // 4 node-waves per 256-thread block
  int nbw2 = (N + 7) / 8;
  dim3 gsplit(nbw, 2);      // feature-split 64-dim gathers

  // GCN1: agg16 = raw agg of x16; h1 = relu(agg16 @ W1 + b1)
  gather16_kernel<<<nbw2, 256, 0, stream>>>(rowptr, deg, csr, dinv_g, x16, a16, N);
  rowmm16f_kernel<<<nb16, 64, 0, stream>>>(a16, w_gcn1, b_gcn1, bufA, N);
  // GCN2: aggB = raw agg of h1; h2 = relu(aggB @ W2 + b2)
  gather_kernel<0><<<gsplit, 256, 0, stream>>>(rowptr, deg, csr, dinv_g, bufA, nullptr, bufB, N);
  gcn2_mfma_kernel<<<nb64, 256, 0, stream>>>(bufB, Wpk2, b_gcn2, bufA, N);

  // 3x GCLSTM: bufA = X -> H in place; layer 3 fuses the final linear
  for (int l = 0; l < 3; ++l) {
    gather_kernel<1><<<gsplit, 256, 0, stream>>>(rowptr, deg, csr, dinv_c, bufA, nullptr, bufB, N);
    gather_kernel<2><<<gsplit, 256, 0, stream>>>(rowptr, deg, csr, dinv_c, bufB, bufA, bufC, N);
    if (l < 2) {
      gate_mfma_kernel<0><<<nb64, 256, 0, stream>>>(bufA, bufB, bufC, Wpk + (size_t)l * 36864,
                                                    bx[l], bh[l], bg[l], wc[l], bufA,
                                                    nullptr, nullptr, nullptr, N);
    } else {
      gate_mfma_kernel<1><<<nb64, 256, 0, stream>>>(bufA, bufB, bufC, Wpk + (size_t)l * 36864,
                                                    bx[l], bh[l], bg[l], wc[l], nullptr,
                                                    lin_w, lin_b, out, N);
    }
  }
}

// Round 7
// 397.014 us; speedup vs baseline: 1.2668x; 1.2668x over previous
//
#include <hip/hip_runtime.h>

// Social-STGCN forward: 2x GCN(improved) + 3x GCLSTM(K=3 Cheb, H=C=0) + linear.
// N=50000 nodes, E=800000 edges, D=64.
//
// Exact simplifications (H=C=0 per cell): gh(g)=bh[g]; f gate dead; Cn=i*t.
// Cheb terms z1=lhat(x), z2=2*lhat(z1)-x shared across gates.
// Aggregation commutes with feature matmul -> GCNs gather raw features first.
// Gathers read PRE-SCALED tables (P = dinv*x): sum of rows only, no per-edge
// dinv load/mul. Self-loop term uses 2*dt^2*x_t == 2*dt*P_t. Producers write
// the dinv-scaled twin where the next gather needs it.
// NOTE: feature-split gather (r6) REVERTED — it doubled HBM fetch (128B lines
// fetched per 64B half, FETCH_SIZE 67.7MB/dispatch).
// Gate matmul + GCN2 matmul on MFMA fp16; layer-3 gate fuses relu+linear.
// csr stored as ushort (N<65536).

typedef _Float16 half8 __attribute__((ext_vector_type(8)));
typedef float f32x4 __attribute__((ext_vector_type(4)));

// ---------- CSR build ----------
__global__ void count_deg_kernel(const int* __restrict__ ei, int* __restrict__ deg, int E) {
  int e = blockIdx.x * blockDim.x + threadIdx.x;
  if (e < E) atomicAdd(&deg[ei[E + e]], 1);
}

__global__ void scan_block_sums(const int* __restrict__ deg, int* __restrict__ bsum, int n) {
  int tid = threadIdx.x;
  int i = blockIdx.x * 256 + tid;
  int v = (i < n) ? deg[i] : 0;
  for (int off = 32; off; off >>= 1) v += __shfl_down(v, off);
  __shared__ int ws[4];
  int lane = tid & 63, wid = tid >> 6;
  if (lane == 0) ws[wid] = v;
  __syncthreads();
  if (tid == 0) bsum[blockIdx.x] = ws[0] + ws[1] + ws[2] + ws[3];
}

// per-block exclusive scan of deg + block offset from raw bsum; fills cursor + dinvs.
__global__ void scan_final(const int* __restrict__ deg, const int* __restrict__ bsum, int nb,
                           int* __restrict__ rowptr, int* __restrict__ cursor,
                           float* __restrict__ dg, float* __restrict__ dc, int n) {
  __shared__ int tmp[256];
  __shared__ int ws[4];
  __shared__ int base_sh;
  int tid = threadIdx.x;
  int v0 = (tid < nb && tid < (int)blockIdx.x) ? bsum[tid] : 0;
  for (int off = 32; off; off >>= 1) v0 += __shfl_down(v0, off);
  if ((tid & 63) == 0) ws[tid >> 6] = v0;
  __syncthreads();
  if (tid == 0) base_sh = ws[0] + ws[1] + ws[2] + ws[3];
  int i = blockIdx.x * 256 + tid;
  int v = (i < n) ? deg[i] : 0;
  tmp[tid] = v;
  __syncthreads();
  for (int off = 1; off < 256; off <<= 1) {
    int t = (tid >= off) ? tmp[tid - off] : 0;
    __syncthreads();
    tmp[tid] += t;
    __syncthreads();
  }
  if (i < n) {
    int excl = tmp[tid] - v + base_sh;
    rowptr[i] = excl;
    cursor[i] = excl;
    dg[i] = rsqrtf((float)v + 2.f);
    dc[i] = (v > 0) ? rsqrtf((float)v) : 0.f;
  }
}

__global__ void fill_kernel(const int* __restrict__ ei, int* __restrict__ cursor,
                            unsigned short* __restrict__ csr, int E) {
  int e = blockIdx.x * blockDim.x + threadIdx.x;
  if (e < E) {
    int d = ei[E + e];
    int pos = atomicAdd(&cursor[d], 1);
    csr[pos] = (unsigned short)ei[e];
  }
}

// ---------- cast+scale x (N x 16 fp32) -> fp16 scaled by dinv_g ----------
__global__ void cast_x16_kernel(const float* __restrict__ x, const float* __restrict__ dg,
                                _Float16* __restrict__ x16s, int total) {
  int i = blockIdx.x * blockDim.x + threadIdx.x;
  if (i < total) x16s[i] = (_Float16)(dg[i >> 4] * x[i]);
}

// ---------- pack gate weights -> fp16 MFMA B-fragment layout ----------
// Wpk[l][g][kc][nt][lane][j]; g in {i,c,o} = src gates {0,2,3}; k = kc*32 + klo,
// klo = (lane>>4)*8 + j; n = nt*16 + (lane&15). Source wx: [4][3][64][64].
__global__ void pack_w_kernel(const float* __restrict__ wx0, const float* __restrict__ wx1,
                              const float* __restrict__ wx2, _Float16* __restrict__ Wpk) {
  int idx = blockIdx.x * 256 + threadIdx.x;
  if (idx >= 3 * 3 * 192 * 64) return;
  int l = idx / 36864;
  int r = idx % 36864;
  int g = r / 12288;
  int r2 = r % 12288;
  int k = r2 / 64;   // 0..191
  int n = r2 % 64;
  const float* wx = (l == 0) ? wx0 : (l == 1 ? wx1 : wx2);
  int gs = (g == 0) ? 0 : (g == 1 ? 2 : 3);
  int tau = k >> 6, kd = k & 63;
  float v = wx[(((size_t)gs * 3 + tau) * 64 + kd) * 64 + n];
  int kc = k >> 5, klo = k & 31;
  int lane = ((klo >> 3) << 4) | (n & 15);
  int j = klo & 7;
  int nt = n >> 4;
  size_t dst = ((((size_t)l * 3 + g) * 6 + kc) * 4 + nt) * 512 + (size_t)lane * 8 + j;
  Wpk[dst] = (_Float16)v;
}

// ---------- pack w_gcn2 [64][64] -> B-frag layout [kc2][nt4][lane][8] ----------
__global__ void pack_w2_kernel(const float* __restrict__ W, _Float16* __restrict__ Wpk2) {
  int idx = blockIdx.x * 256 + threadIdx.x;
  if (idx >= 4096) return;
  int k = idx >> 6, n = idx & 63;
  float v = W[k * 64 + n];
  int kc = k >> 5, klo = k & 31;
  int lane = ((klo >> 3) << 4) | (n & 15);
  int j = klo & 7;
  int nt = n >> 4;
  Wpk2[(((size_t)kc * 4 + nt) * 64 + lane) * 8 + j] = (_Float16)v;
}

// ---------- gather16: agg of scaled 16-dim rows; 2 nodes/wave ----------
// OUT[t] = dt*acc + 2*dt*INs[t]   (INs = dg-scaled x16)
__global__ void gather16_kernel(const int* __restrict__ rowptr, const int* __restrict__ deg,
                                const unsigned short* __restrict__ csr,
                                const float* __restrict__ dinv,
                                const _Float16* __restrict__ INs,
                                _Float16* __restrict__ OUT, int n) {
  int tid = threadIdx.x;
  int node = blockIdx.x * (blockDim.x >> 5) + (tid >> 5);
  if (node >= n) return;
  int l32 = tid & 31;
  int eg = l32 >> 1;   // 16 edge slots
  int c8 = l32 & 1;    // half8 chunk (8 feats)
  int beg = rowptr[node], end = beg + deg[node];
  const half8* IN8 = (const half8*)INs;  // 2 per row
  float acc[8];
#pragma unroll
  for (int j = 0; j < 8; ++j) acc[j] = 0.f;
  for (int p = beg + eg; p < end; p += 16) {
    int s = csr[p];
    half8 v = IN8[(size_t)s * 2 + c8];
#pragma unroll
    for (int j = 0; j < 8; ++j) acc[j] += (float)v[j];
  }
#pragma unroll
  for (int j = 0; j < 8; ++j) {
    acc[j] += __shfl_xor(acc[j], 2);
    acc[j] += __shfl_xor(acc[j], 4);
    acc[j] += __shfl_xor(acc[j], 8);
    acc[j] += __shfl_xor(acc[j], 16);
  }
  if (eg == 0) {
    float dt = dinv[node];
    half8 self = IN8[(size_t)node * 2 + c8];
    half8 r;
#pragma unroll
    for (int j = 0; j < 8; ++j) r[j] = (_Float16)(dt * acc[j] + 2.f * dt * (float)self[j]);
    ((half8*)OUT)[(size_t)node * 2 + c8] = r;
  }
}

// ---------- gather (64-dim): one wave/node, 8 edge-slots x 8 half8-lanes ----------
// All inputs are dinv-scaled tables; inner loop = pure row sum.
// MODE 0: GCN  -> OUT  = dt*acc + 2*dt*INs[node]          (unscaled agg)
// MODE 1: z1   -> OUT  = -dt*acc (z1);  OUTs = -dt^2*acc  (dc-scaled z1)
// MODE 2: z2   -> OUT  = -2*dt*acc - AUX[node]            (AUX = unscaled X)
template <int MODE>
__global__ void gather_kernel(const int* __restrict__ rowptr, const int* __restrict__ deg,
                              const unsigned short* __restrict__ csr,
                              const float* __restrict__ dinv,
                              const _Float16* __restrict__ INs, const _Float16* __restrict__ AUX,
                              _Float16* __restrict__ OUT, _Float16* __restrict__ OUTs, int n) {
  int node = blockIdx.x * (blockDim.x >> 6) + (threadIdx.x >> 6);
  if (node >= n) return;
  int lane = threadIdx.x & 63;
  int eg = lane >> 3;   // edge slot 0..7
  int c8 = lane & 7;    // half8 chunk of the 64-feature row
  int beg = rowptr[node], end = beg + deg[node];
  const half8* IN8 = (const half8*)INs;
  float acc[8];
#pragma unroll
  for (int j = 0; j < 8; ++j) acc[j] = 0.f;
  for (int p = beg + eg; p < end; p += 8) {
    int s = csr[p];
    half8 v = IN8[(size_t)s * 8 + c8];
#pragma unroll
    for (int j = 0; j < 8; ++j) acc[j] += (float)v[j];
  }
#pragma unroll
  for (int j = 0; j < 8; ++j) {
    acc[j] += __shfl_xor(acc[j], 8);
    acc[j] += __shfl_xor(acc[j], 16);
    acc[j] += __shfl_xor(acc[j], 32);
  }
  if (eg == 0) {
    float dt = dinv[node];
    size_t o8 = (size_t)node * 8 + c8;
    half8 r;
    if (MODE == 0) {
      half8 self = IN8[o8];
#pragma unroll
      for (int j = 0; j < 8; ++j) r[j] = (_Float16)(dt * acc[j] + 2.f * dt * (float)self[j]);
      ((half8*)OUT)[o8] = r;
    } else if (MODE == 1) {
      half8 rs;
#pragma unroll
      for (int j = 0; j < 8; ++j) {
        float z = -dt * acc[j];
        r[j] = (_Float16)z;
        rs[j] = (_Float16)(dt * z);
      }
      ((half8*)OUT)[o8] = r;
      ((half8*)OUTs)[o8] = rs;
    } else {
      half8 xx = ((const half8*)AUX)[o8];
#pragma unroll
      for (int j = 0; j < 8; ++j) r[j] = (_Float16)(-2.f * dt * acc[j] - (float)xx[j]);
      ((half8*)OUT)[o8] = r;
    }
  }
}

// ---------- GCN1: h1s = dg * relu(A16[n][16] @ W[16][64] + b) ----------
__global__ __launch_bounds__(64) void rowmm16f_kernel(const _Float16* __restrict__ A,
                                                      const float* __restrict__ W,
                                                      const float* __restrict__ bias,
                                                      const float* __restrict__ dg,
                                                      _Float16* __restrict__ OUTs, int n) {
  __shared__ float xt[256];
  int tid = threadIdx.x;
  int n0 = blockIdx.x * 16;
  for (int idx = tid; idx < 256; idx += 64) {
    int row = idx >> 4, col = idx & 15;
    int gr = min(n0 + row, n - 1);
    xt[idx] = (float)A[(size_t)gr * 16 + col];
  }
  __syncthreads();
  float acc[16];
  float b = bias[tid];
#pragma unroll
  for (int t = 0; t < 16; ++t) acc[t] = b;
  for (int k = 0; k < 16; ++k) {
    float w = W[k * 64 + tid];
#pragma unroll
    for (int t = 0; t < 16; ++t) acc[t] += xt[t * 16 + k] * w;
  }
#pragma unroll
  for (int t = 0; t < 16; ++t) {
    int node = n0 + t;
    if (node < n) OUTs[(size_t)node * 64 + tid] = (_Float16)(dg[node] * fmaxf(acc[t], 0.f));
  }
}

// ---------- GCN2 on MFMA: h2 = relu(A @ W2 + b); writes h2 and dc*h2 ----------
__global__ __launch_bounds__(256) void gcn2_mfma_kernel(
    const _Float16* __restrict__ A, const _Float16* __restrict__ W2,
    const float* __restrict__ bias, const float* __restrict__ dc,
    _Float16* __restrict__ OUT, _Float16* __restrict__ OUTs, int n) {
  int tid = threadIdx.x;
  int wid = tid >> 6, lane = tid & 63;
  int n0 = blockIdx.x * 64;
  int row = n0 + wid * 16 + (lane & 15);
  int rowc = min(row, n - 1);
  int ksub = (lane >> 4) << 3;
  int dbase = lane & 15;
  const _Float16* Wlane = W2 + (size_t)lane * 8;
  f32x4 acc[4];
#pragma unroll
  for (int nt = 0; nt < 4; ++nt) {
    float b = bias[nt * 16 + dbase];
    acc[nt] = (f32x4){b, b, b, b};
  }
#pragma unroll
  for (int kc = 0; kc < 2; ++kc) {
    half8 a = *(const half8*)&A[(size_t)rowc * 64 + (kc << 5) + ksub];
#pragma unroll
    for (int nt = 0; nt < 4; ++nt) {
      half8 b = *(const half8*)(Wlane + (size_t)(kc * 4 + nt) * 512);
      acc[nt] = __builtin_amdgcn_mfma_f32_16x16x32_f16(a, b, acc[nt], 0, 0, 0);
    }
  }
  int mrow = n0 + wid * 16 + ((lane >> 4) << 2);
#pragma unroll
  for (int nt = 0; nt < 4; ++nt) {
    int d = nt * 16 + dbase;
#pragma unroll
    for (int r = 0; r < 4; ++r) {
      int node = mrow + r;
      if (node < n) {
        float h = fmaxf(acc[nt][r], 0.f);
        OUT[(size_t)node * 64 + d] = (_Float16)h;
        OUTs[(size_t)node * 64 + d] = (_Float16)(dc[node] * h);
      }
    }
  }
}

// ---------- MFMA gate kernel: 64 nodes/block, 16 nodes/wave, no LDS ----------
// FINAL=0: writes H and dc*H.  FINAL=1: fuses out = relu(H) @ lin_w + lin_b.
template <int FINAL>
__global__ __launch_bounds__(256) void gate_mfma_kernel(
    const _Float16* __restrict__ X, const _Float16* __restrict__ Z1,
    const _Float16* __restrict__ Z2,
    const _Float16* __restrict__ Wl,  // packed [3][6][4][64][8] for this layer
    const float* __restrict__ bx, const float* __restrict__ bh, const float* __restrict__ bg,
    const float* __restrict__ wc, const float* __restrict__ dc,
    _Float16* __restrict__ H, _Float16* __restrict__ Hs,
    const float* __restrict__ lw, const float* __restrict__ lb,
    float* __restrict__ out, int n) {
  int tid = threadIdx.x;
  int wid = tid >> 6, lane = tid & 63;
  int n0 = blockIdx.x * 64;
  int row = n0 + wid * 16 + (lane & 15);
  int rowc = min(row, n - 1);               // clamped load row (stores guarded)
  int ksub = (lane >> 4) << 3;              // 0,8,16,24
  const _Float16* Wlane = Wl + (size_t)lane * 8;
  int dbase = lane & 15;

  f32x4 acc[3][4];
#pragma unroll
  for (int g = 0; g < 3; ++g) {
    int gs = (g == 0) ? 0 : (g == 1 ? 2 : 3);
#pragma unroll
    for (int nt = 0; nt < 4; ++nt) {
      int d = nt * 16 + dbase;
      float b = bx[gs * 64 + d] + bh[gs * 64 + d] + bg[gs * 64 + d];
      acc[g][nt] = (f32x4){b, b, b, b};
    }
  }
  const _Float16* T[3] = {X, Z1, Z2};
#pragma unroll
  for (int kc = 0; kc < 6; ++kc) {
    const _Float16* t = T[kc >> 1];
    half8 a = *(const half8*)&t[(size_t)rowc * 64 + ((kc & 1) << 5) + ksub];
#pragma unroll
    for (int g = 0; g < 3; ++g) {
#pragma unroll
      for (int nt = 0; nt < 4; ++nt) {
        half8 b = *(const half8*)(Wlane + (size_t)((g * 6 + kc) * 4 + nt) * 512);
        acc[g][nt] = __builtin_amdgcn_mfma_f32_16x16x32_f16(a, b, acc[g][nt], 0, 0, 0);
      }
    }
  }
  int mrow = n0 + wid * 16 + ((lane >> 4) << 2);
  float po[4][3];
  if (FINAL) {
#pragma unroll
    for (int r = 0; r < 4; ++r) { po[r][0] = 0.f; po[r][1] = 0.f; po[r][2] = 0.f; }
  }
#pragma unroll
  for (int nt = 0; nt < 4; ++nt) {
    int d = nt * 16 + dbase;
    float wcd = wc[128 + d];
#pragma unroll
    for (int r = 0; r < 4; ++r) {
      float ig = 1.f / (1.f + expf(-acc[0][nt][r]));
      float tt = tanhf(acc[1][nt][r]);
      float Cn = ig * tt;
      float og = 1.f / (1.f + expf(-(acc[2][nt][r] + wcd * Cn)));
      float h = og * tanhf(Cn);
      if (FINAL) {
        float rl = fmaxf(h, 0.f);
        po[r][0] += rl * lw[d * 3 + 0];
        po[r][1] += rl * lw[d * 3 + 1];
        po[r][2] += rl * lw[d * 3 + 2];
      } else {
        int node = mrow + r;
        if (node < n) {
          H[(size_t)node * 64 + d] = (_Float16)h;
          Hs[(size_t)node * 64 + d] = (_Float16)(dc[node] * h);
        }
      }
    }
  }
  if (FINAL) {
#pragma unroll
    for (int m = 1; m < 16; m <<= 1) {
#pragma unroll
      for (int r = 0; r < 4; ++r) {
        po[r][0] += __shfl_xor(po[r][0], m);
        po[r][1] += __shfl_xor(po[r][1], m);
        po[r][2] += __shfl_xor(po[r][2], m);
      }
    }
    if (dbase == 0) {
#pragma unroll
      for (int r = 0; r < 4; ++r) {
        int node = mrow + r;
        if (node < n) {
          out[(size_t)node * 3 + 0] = po[r][0] + lb[0];
          out[(size_t)node * 3 + 1] = po[r][1] + lb[1];
          out[(size_t)node * 3 + 2] = po[r][2] + lb[2];
        }
      }
    }
  }
}

extern "C" void kernel_launch(void* const* d_in, const int* in_sizes, int n_in,
                              void* d_out, int out_size, void* d_ws, size_t ws_size,
                              hipStream_t stream) {
  const float* x      = (const float*)d_in[0];
  const int*   ei     = (const int*)d_in[1];
  const float* w_gcn1 = (const float*)d_in[2];
  const float* b_gcn1 = (const float*)d_in[3];
  const float* w_gcn2 = (const float*)d_in[4];
  const float* b_gcn2 = (const float*)d_in[5];
  const float* wx[3]  = {(const float*)d_in[6],  (const float*)d_in[12], (const float*)d_in[18]};
  const float* bx[3]  = {(const float*)d_in[7],  (const float*)d_in[13], (const float*)d_in[19]};
  const float* bh[3]  = {(const float*)d_in[9],  (const float*)d_in[15], (const float*)d_in[21]};
  const float* wc[3]  = {(const float*)d_in[10], (const float*)d_in[16], (const float*)d_in[22]};
  const float* bg[3]  = {(const float*)d_in[11], (const float*)d_in[17], (const float*)d_in[23]};
  const float* lin_w  = (const float*)d_in[24];
  const float* lin_b  = (const float*)d_in[25];
  float* out = (float*)d_out;

  int N = in_sizes[0] / 16;
  int E = in_sizes[1] / 2;
  int nsb = (N + 255) / 256;

  char* ws = (char*)d_ws;
  size_t off = 0;
  auto alloc = [&](size_t bytes) {
    void* p = ws + off;
    off = (off + bytes + 255) & ~(size_t)255;
    return p;
  };
  int* deg        = (int*)alloc((size_t)N * 4);
  int* rowptr     = (int*)alloc((size_t)N * 4);
  int* cursor     = (int*)alloc((size_t)N * 4);
  int* bsum       = (int*)alloc((size_t)nsb * 4);
  unsigned short* csr = (unsigned short*)alloc((size_t)E * 2);
  float* dinv_g   = (float*)alloc((size_t)N * 4);
  float* dinv_c   = (float*)alloc((size_t)N * 4);
  _Float16* Wpk   = (_Float16*)alloc((size_t)3 * 36864 * 2);
  _Float16* Wpk2  = (_Float16*)alloc((size_t)4096 * 2);
  _Float16* x16s  = (_Float16*)alloc((size_t)N * 16 * 2);
  _Float16* a16   = (_Float16*)alloc((size_t)N * 16 * 2);
  _Float16* bufA  = (_Float16*)alloc((size_t)N * 64 * 2);   // X (unscaled)
  _Float16* bufAs = (_Float16*)alloc((size_t)N * 64 * 2);   // dc*X
  _Float16* bufB  = (_Float16*)alloc((size_t)N * 64 * 2);   // z1 / h1s
  _Float16* bufBs = (_Float16*)alloc((size_t)N * 64 * 2);   // dc*z1
  _Float16* bufC  = (_Float16*)alloc((size_t)N * 64 * 2);   // z2 / gcn2-agg
  (void)ws_size; (void)n_in; (void)out_size;

  const int tb = 256;
  hipMemsetAsync(deg, 0, (size_t)N * 4, stream);
  count_deg_kernel<<<(E + tb - 1) / tb, tb, 0, stream>>>(ei, deg, E);
  scan_block_sums<<<nsb, 256, 0, stream>>>(deg, bsum, N);
  scan_final<<<nsb, 256, 0, stream>>>(deg, bsum, nsb, rowptr, cursor, dinv_g, dinv_c, N);
  fill_kernel<<<(E + tb - 1) / tb, tb, 0, stream>>>(ei, cursor, csr, E);
  pack_w_kernel<<<(110592 + 255) / 256, 256, 0, stream>>>(wx[0], wx[1], wx[2], Wpk);
  pack_w2_kernel<<<16, 256, 0, stream>>>(w_gcn2, Wpk2);
  cast_x16_kernel<<<(N * 16 + 255) / 256, 256, 0, stream>>>(x, dinv_g, x16s, N * 16);

  int nb16 = (N + 15) / 16;
  int nb64 = (N + 63) / 64;
  int nbw  = (N + 3) / 4;   // 4 node-waves per 256-thread block
  int nbw2 = (N + 7) / 8;

  // GCN1: a16 = agg(x16s); h1s = dg*relu(a16 @ W1 + b1)
  gather16_kernel<<<nbw2, 256, 0, stream>>>(rowptr, deg, csr, dinv_g, x16s, a16, N);
  rowmm16f_kernel<<<nb16, 64, 0, stream>>>(a16, w_gcn1, b_gcn1, dinv_g, bufB, N);
  // GCN2: aggC = agg(h1s); h2 = relu(aggC @ W2 + b2) -> bufA (+ dc-scaled bufAs)
  gather_kernel<0><<<nbw, 256, 0, stream>>>(rowptr, deg, csr, dinv_g, bufB, nullptr, bufC, nullptr, N);
  gcn2_mfma_kernel<<<nb64, 256, 0, stream>>>(bufC, Wpk2, b_gcn2, dinv_c, bufA, bufAs, N);

  // 3x GCLSTM: bufA/bufAs = X -> H in place; layer 3 fuses the final linear
  for (int l = 0; l < 3; ++l) {
    gather_kernel<1><<<nbw, 256, 0, stream>>>(rowptr, deg, csr, dinv_c, bufAs, nullptr, bufB, bufBs, N);
    gather_kernel<2><<<nbw, 256, 0, stream>>>(rowptr, deg, csr, dinv_c, bufBs, bufA, bufC, nullptr, N);
    if (l < 2) {
      gate_mfma_kernel<0><<<nb64, 256, 0, stream>>>(bufA, bufB, bufC, Wpk + (size_t)l * 36864,
                                                    bx[l], bh[l], bg[l], wc[l], dinv_c,
                                                    bufA, bufAs, nullptr, nullptr, nullptr, N);
    } else {
      gate_mfma_kernel<1><<<nb64, 256, 0, stream>>>(bufA, bufB, bufC, Wpk + (size_t)l * 36864,
                                                    bx[l], bh[l], bg[l], wc[l], dinv_c,
                                                    nullptr, nullptr, lin_w, lin_b, out, N);
    }
  }
}